// Round 4
// baseline (303.950 us; speedup 1.0000x reference)
//
#include <hip/hip_runtime.h>
#include <math.h>

#define DIMK 2048
#define NSEQ 4096

typedef short bf16x4 __attribute__((ext_vector_type(4)));
typedef short bf16x8 __attribute__((ext_vector_type(8)));
typedef float f32x16 __attribute__((ext_vector_type(16)));
typedef unsigned short u16;

__device__ __forceinline__ u16 f32_to_bf16(float f) {
  unsigned u = __float_as_uint(f);
  u += 0x7fffu + ((u >> 16) & 1u);   // round-to-nearest-even
  return (u16)(u >> 16);
}

__device__ __forceinline__ void async16(const u16* g, u16* l) {
  __builtin_amdgcn_global_load_lds(
      (const __attribute__((address_space(1))) unsigned int*)g,
      (__attribute__((address_space(3))) unsigned int*)l,
      16, 0, 0);
}

// All bf16 buffers use an intra-row XOR-swizzled layout:
//   memory 8B-unit w of row r holds LOGICAL unit (w & ~15) | ((w ^ r) & 15).
// (512 units per 2048-elem row; swizzle closed within 128 B groups, so any
// 128 B-aligned K-window is self-contained.)

// -------- fused fp32 -> bf16 cast (swizzled output), one 8B unit/thread ----
__global__ __launch_bounds__(256) void cast3_swz(
    const float* __restrict__ x, const float* __restrict__ wq,
    const float* __restrict__ wk, u16* __restrict__ xb,
    u16* __restrict__ wqb, u16* __restrict__ wkb) {
  const int xU = NSEQ * DIMK / 4;   // 8B units
  const int wU = DIMK * DIMK / 4;
  int i = blockIdx.x * 256 + threadIdx.x;
  const float* src;
  u16* dst;
  int j;
  if (i < xU) { src = x; dst = xb; j = i; }
  else if (i < xU + wU) { src = wq; dst = wqb; j = i - xU; }
  else { src = wk; dst = wkb; j = i - xU - wU; }
  int r = j >> 9;                              // 512 units per row
  int sj = (j & ~15) | ((j ^ r) & 15);         // logical unit stored at j
  float4 v = ((const float4*)src)[sj];
  ushort4 o;
  o.x = f32_to_bf16(v.x);
  o.y = f32_to_bf16(v.y);
  o.z = f32_to_bf16(v.z);
  o.w = f32_to_bf16(v.w);
  ((ushort4*)dst)[j] = o;
}

// ---- NT bf16 GEMM mainloop: 128x128 tile, BK=64, 32x32x16 MFMA (2x2/wave).
// Memory is pre-swizzled, so staging is plain sequential global_load_lds and
// frag reads are 2x ds_read_b64 at physical unit (2l)^(lane&15) / ^1 —
// 16 bank-pair positions, 2 lanes each -> conflict-free.
__device__ __forceinline__ void gemm_mainloop_128(
    const u16* __restrict__ Abase, const u16* __restrict__ Bbase,
    u16* sA, u16* sB, f32x16 acc[2][2], int tid, int wm, int wn, int lane) {
  const int K = DIMK;
  int rowS[4], glOff[4];
#pragma unroll
  for (int c = 0; c < 4; ++c) {
    int s = c * 256 + tid;
    glOff[c] = (s >> 3) * K + (s & 7) * 8;  // sequential 16B chunks per row
    rowS[c] = s * 8;                        // LDS elem offset (16 B per slot)
  }
  const int r31 = lane & 31;
  const int q = lane >> 5;
  const int m = lane & 15;
  int rowA[2], rowB[2], c0[4];
#pragma unroll
  for (int i = 0; i < 2; ++i) {
    rowA[i] = (wm + i * 32 + r31) * 64;
    rowB[i] = (wn + i * 32 + r31) * 64;
  }
#pragma unroll
  for (int ks = 0; ks < 4; ++ks) {
    int l = (ks << 1) | q;                  // logical 16B chunk for this frag
    c0[ks] = ((2 * l) ^ m) * 4;             // elem offset of physical 8B unit
  }

  for (int k0 = 0; k0 < K; k0 += 64) {
#pragma unroll
    for (int c = 0; c < 4; ++c) {
      async16(Abase + glOff[c] + k0, sA + rowS[c]);
      async16(Bbase + glOff[c] + k0, sB + rowS[c]);
    }
    __syncthreads();
#pragma unroll
    for (int ks = 0; ks < 4; ++ks) {
      const int p0 = c0[ks];
      const int p1 = p0 ^ 4;
      bf16x8 af[2], bfv[2];
#pragma unroll
      for (int i = 0; i < 2; ++i) {
        bf16x4 alo = *(const bf16x4*)&sA[rowA[i] + p0];
        bf16x4 ahi = *(const bf16x4*)&sA[rowA[i] + p1];
        af[i] = __builtin_shufflevector(alo, ahi, 0, 1, 2, 3, 4, 5, 6, 7);
        bf16x4 blo = *(const bf16x4*)&sB[rowB[i] + p0];
        bf16x4 bhi = *(const bf16x4*)&sB[rowB[i] + p1];
        bfv[i] = __builtin_shufflevector(blo, bhi, 0, 1, 2, 3, 4, 5, 6, 7);
      }
#pragma unroll
      for (int i = 0; i < 2; ++i)
#pragma unroll
        for (int j = 0; j < 2; ++j)
          acc[i][j] = __builtin_amdgcn_mfma_f32_32x32x16_bf16(
              af[i], bfv[j], acc[i][j], 0, 0, 0);
    }
    __syncthreads();
  }
}

// -------- GEMM1: Q = scale*(x Wq^T + bq) ; K = x Wk^T + bk  (z selects) ----
__global__ __launch_bounds__(256) void gemm_qk(
    const u16* __restrict__ X,
    const u16* __restrict__ Wq, const u16* __restrict__ Wk,
    const float* __restrict__ bq, const float* __restrict__ bk,
    u16* __restrict__ Qo, u16* __restrict__ Ko, float qscale) {
  const u16* Bmat = blockIdx.z ? Wk : Wq;
  const float* bias = blockIdx.z ? bk : bq;
  u16* Out = blockIdx.z ? Ko : Qo;
  const float sc = blockIdx.z ? 1.0f : qscale;

  __shared__ u16 sA[128 * 64];
  __shared__ u16 sB[128 * 64];

  const int tid = threadIdx.x;
  const int lane = tid & 63;
  const int wid = tid >> 6;
  const int rowBase = blockIdx.y * 128;
  const int colBase = blockIdx.x * 128;
  const int wm = (wid >> 1) * 64;
  const int wn = (wid & 1) * 64;

  f32x16 acc[2][2] = {};
  gemm_mainloop_128(X + (size_t)rowBase * DIMK, Bmat + (size_t)colBase * DIMK,
                    sA, sB, acc, tid, wm, wn, lane);

  // C/D layout (32x32): col = lane&31, row = (r&3) + 8*(r>>2) + 4*(lane>>5)
  // Output written in the swizzled bf16 layout (col bits 5:2 ^= row&15).
  const int r31 = lane & 31;
  const int q4 = (lane >> 5) * 4;
#pragma unroll
  for (int j = 0; j < 2; ++j) {
    const int col = colBase + wn + j * 32 + r31;
    const float bv = bias[col];
#pragma unroll
    for (int i = 0; i < 2; ++i) {
#pragma unroll
      for (int r = 0; r < 16; ++r) {
        const int row = rowBase + wm + i * 32 + (r & 3) + 8 * (r >> 2) + q4;
        const int mc =
            (col & ~63) | ((((col >> 2) ^ row) & 15) << 2) | (col & 3);
        Out[(size_t)row * DIMK + mc] = f32_to_bf16((acc[i][j][r] + bv) * sc);
      }
    }
  }
}

// -------- GEMM2: scores = Q K^T  (scale pre-folded into Q; fp32 out) ------
__global__ __launch_bounds__(256) void gemm_scores(
    const u16* __restrict__ Qi, const u16* __restrict__ Ki,
    float* __restrict__ out) {
  __shared__ u16 sA[128 * 64];
  __shared__ u16 sB[128 * 64];

  const int tid = threadIdx.x;
  const int lane = tid & 63;
  const int wid = tid >> 6;
  const int rowBase = blockIdx.y * 128;
  const int colBase = blockIdx.x * 128;
  const int wm = (wid >> 1) * 64;
  const int wn = (wid & 1) * 64;

  f32x16 acc[2][2] = {};
  gemm_mainloop_128(Qi + (size_t)rowBase * DIMK, Ki + (size_t)colBase * DIMK,
                    sA, sB, acc, tid, wm, wn, lane);

  const int r31 = lane & 31;
  const int q4 = (lane >> 5) * 4;
#pragma unroll
  for (int j = 0; j < 2; ++j) {
    const int col = colBase + wn + j * 32 + r31;
#pragma unroll
    for (int i = 0; i < 2; ++i) {
#pragma unroll
      for (int r = 0; r < 16; ++r) {
        const int row = rowBase + wm + i * 32 + (r & 3) + 8 * (r >> 2) + q4;
        out[(size_t)row * NSEQ + col] = acc[i][j][r];
      }
    }
  }
}

extern "C" void kernel_launch(void* const* d_in, const int* in_sizes, int n_in,
                              void* d_out, int out_size, void* d_ws, size_t ws_size,
                              hipStream_t stream) {
  const float* x = (const float*)d_in[0];
  const float* Wq = (const float*)d_in[1];
  const float* bq = (const float*)d_in[2];
  const float* Wk = (const float*)d_in[3];
  const float* bk = (const float*)d_in[4];
  // d_in[5], d_in[6] (W_v, b_v) unused — V never reaches the output.
  float* out = (float*)d_out;

  // workspace layout (64 MB total), all bf16 buffers in swizzled layout
  u16* xb = (u16*)d_ws;                       // 4096x2048 bf16 (16 MB)
  u16* wqb = xb + (size_t)NSEQ * DIMK;        // 2048x2048 bf16 (8 MB)
  u16* wkb = wqb + (size_t)DIMK * DIMK;       // 8 MB
  u16* qb = wkb + (size_t)DIMK * DIMK;        // 16 MB
  u16* kb = qb + (size_t)NSEQ * DIMK;         // 16 MB

  const int totalU = (NSEQ * DIMK + 2 * DIMK * DIMK) / 4;
  cast3_swz<<<totalU / 256, 256, 0, stream>>>(x, Wq, Wk, xb, wqb, wkb);

  const float scale = 1.0f / sqrtf((float)DIMK);
  gemm_qk<<<dim3(DIMK / 128, NSEQ / 128, 2), 256, 0, stream>>>(
      xb, wqb, wkb, bq, bk, qb, kb, scale);

  gemm_scores<<<dim3(NSEQ / 128, NSEQ / 128, 1), 256, 0, stream>>>(qb, kb, out);
}